// Round 9
// baseline (194.270 us; speedup 1.0000x reference)
//
#include <hip/hip_runtime.h>
#include <math.h>

#define DIMH 256        // D
#define NB   32         // batch
#define E_TOT 43234
#define TE   32         // entities per block  (1352 blocks = 5.28/CU)
#define DK   32         // d-chunk staged in LDS
#define NC   (DIMH / DK)  // 8 chunks
// reference: phase = rel / (REL_RANGE/PI); REL_RANGE/PI = 0.03125/PI
#define PHASE_DIV 0.009947183943243459f

typedef float v2f __attribute__((ext_vector_type(2)));
typedef float v4f __attribute__((ext_vector_type(4)));

// Kernel 1: rotate head by relation phase; emit rot directly in the
// interleaved v4f layout (re_2p, re_2p+1, im_2p, im_2p+1) per (b, dpair)
// so dist stages it with a single float4 load -> single LDS store.
__global__ __launch_bounds__(256) void rot_kernel(const float* __restrict__ head,
                                                  const float* __restrict__ rel,
                                                  float4* __restrict__ rot_v4) {
    int i  = blockIdx.x * 256 + threadIdx.x;   // 0..4095
    int b  = i >> 7;
    int dp = i & 127;
    int d0 = dp * 2;
    float4 w;
    {
        float re_h = head[b * 2 * DIMH + d0];
        float im_h = head[b * 2 * DIMH + DIMH + d0];
        float s, c;
        sincosf(rel[b * DIMH + d0] / PHASE_DIV, &s, &c);
        w.x = re_h * c - im_h * s;
        w.z = re_h * s + im_h * c;
    }
    {
        float re_h = head[b * 2 * DIMH + d0 + 1];
        float im_h = head[b * 2 * DIMH + DIMH + d0 + 1];
        float s, c;
        sincosf(rel[b * DIMH + d0 + 1] / PHASE_DIV, &s, &c);
        w.y = re_h * c - im_h * s;
        w.w = re_h * s + im_h * c;
    }
    rot_v4[b * (DIMH / 2) + dp] = w;
}

// sqrt WITHOUT the trans pipe: rsqrt bit-hack + 1 Newton step, x = s*r1.
// R8 counters showed v_sqrt_f32 (~16 cyc/wave64) consumed ~2/3 of busy
// cycles; this is 4 full-rate scalar + 4 pk ops on the main VALU instead.
// Rel err ~0.1-0.2% (one-sided) -> output bias <~0.5 vs threshold 10.48.
// s=0 -> a=0 -> returns 0 cleanly.
__device__ __forceinline__ v2f nr_sqrt2(v2f s) {
    v2f r0;
    r0.x = __uint_as_float(0x5F375A86u - (__float_as_uint(s.x) >> 1));
    r0.y = __uint_as_float(0x5F375A86u - (__float_as_uint(s.y) >> 1));
    v2f a = s * r0;                       // ~sqrt(s), +-3.4%
    v2f b = a * r0;                       // ~1
    v2f c = -0.5f * b + 1.5f;             // NR correction (pk fma)
    return a * c;                         // sqrt(s) * (1 +- ~0.002)
}

// Kernel 2: block = 32-entity tile x all 256 d, all 32 batches.
// 1352 blocks = 5.28/CU. Direct output stores. LDS element = v4f
// (re0,re1,im0,im1); row stride 17 float4 (R4-verified ~0-conflict).
// Tile reads are 4/16-way lane-broadcasts -> effective LDS ~1.25 B/contrib.
// Per-thread tile: 2 batch x 2 entity.
__global__ __launch_bounds__(256, 6) void dist_kernel(const float* __restrict__ ent,
                                                      const float4* __restrict__ rot_v4,
                                                      float* __restrict__ out) {
    __shared__ v4f s_e[TE][DK / 2 + 1];   // 32 x 17 x 16 B = 8.7 KB
    __shared__ v4f s_r[NB][DK / 2 + 1];   // 32 x 17 x 16 B = 8.7 KB

    const int tid = threadIdx.x;
    const int eb  = blockIdx.x * TE;
    const int ep  = tid & 15;          // entities {ep, ep+16}
    const int bp  = tid >> 4;          // batches {2bp, 2bp+1}

    // ent staging: 256 tasks = 32 rows x 8 quads, 1 per thread (re+im loads)
    const int srow = tid >> 3;                 // 0..31
    const int c4   = tid & 7;                  // quad: d = dk + 4*c4
    const int er   = min(eb + srow, E_TOT - 1);
    // rot staging: 512 float4 = 32 rows x 16 dpairs, 2 per thread
    const int rrow = tid >> 4;                 // 0..15 (and +16)
    const int rdp  = tid & 15;                 // dpair within chunk

    float4 p_re, p_im, p_r0, p_r1;

    auto load_chunk = [&](int c) {
        const int dk = c * DK;
        const float* b0 = &ent[(size_t)er * (2 * DIMH)];
        p_re = *reinterpret_cast<const float4*>(b0 + dk + 4 * c4);
        p_im = *reinterpret_cast<const float4*>(b0 + DIMH + dk + 4 * c4);
        p_r0 = rot_v4[rrow * (DIMH / 2) + c * (DK / 2) + rdp];
        p_r1 = rot_v4[(rrow + 16) * (DIMH / 2) + c * (DK / 2) + rdp];
    };

    v2f acc[2][2];   // [batch j][entity k]
    #pragma unroll
    for (int j = 0; j < 2; ++j)
        #pragma unroll
        for (int k = 0; k < 2; ++k) { acc[j][k].x = 0.f; acc[j][k].y = 0.f; }

    load_chunk(0);

    for (int c = 0; c < NC; ++c) {
        // ---- store prefetched regs to LDS (interleave ent re/im into v4f)
        {
            v4f lo, hi;
            lo.x = p_re.x; lo.y = p_re.y; lo.z = p_im.x; lo.w = p_im.y;
            hi.x = p_re.z; hi.y = p_re.w; hi.z = p_im.z; hi.w = p_im.w;
            s_e[srow][2 * c4]     = lo;
            s_e[srow][2 * c4 + 1] = hi;
            v4f r0, r1;
            r0.x = p_r0.x; r0.y = p_r0.y; r0.z = p_r0.z; r0.w = p_r0.w;
            r1.x = p_r1.x; r1.y = p_r1.y; r1.z = p_r1.z; r1.w = p_r1.w;
            s_r[rrow][rdp]      = r0;
            s_r[rrow + 16][rdp] = r1;
        }
        __syncthreads();

        // ---- issue next chunk's global loads (consumed after next barrier)
        if (c + 1 < NC) load_chunk(c + 1);

        #pragma unroll 4
        for (int p = 0; p < DK / 2; ++p) {
            v4f r0 = s_r[2 * bp][p];
            v4f r1 = s_r[2 * bp + 1][p];
            v4f e0 = s_e[ep][p];
            v4f e1 = s_e[ep + 16][p];

            {   v2f a = r0.xy - e0.xy, b = r0.zw - e0.zw;
                acc[0][0] += nr_sqrt2(a * a + b * b); }
            {   v2f a = r0.xy - e1.xy, b = r0.zw - e1.zw;
                acc[0][1] += nr_sqrt2(a * a + b * b); }
            {   v2f a = r1.xy - e0.xy, b = r1.zw - e0.zw;
                acc[1][0] += nr_sqrt2(a * a + b * b); }
            {   v2f a = r1.xy - e1.xy, b = r1.zw - e1.zw;
                acc[1][1] += nr_sqrt2(a * a + b * b); }
        }
        __syncthreads();
    }

    #pragma unroll
    for (int k = 0; k < 2; ++k) {
        int e = eb + ep + 16 * k;
        if (e < E_TOT) {
            #pragma unroll
            for (int j = 0; j < 2; ++j)
                out[(size_t)(2 * bp + j) * E_TOT + e] = 6.0f - (acc[j][k].x + acc[j][k].y);
        }
    }
}

extern "C" void kernel_launch(void* const* d_in, const int* in_sizes, int n_in,
                              void* d_out, int out_size, void* d_ws, size_t ws_size,
                              hipStream_t stream) {
    const float* head = (const float*)d_in[0];   // (32, 512)
    const float* rel  = (const float*)d_in[1];   // (32, 256)
    const float* ent  = (const float*)d_in[2];   // (43234, 512)
    float4* rot_v4 = (float4*)d_ws;              // 32 * 128 * 16 B = 64 KB

    rot_kernel<<<(NB * DIMH / 2) / 256, 256, 0, stream>>>(head, rel, rot_v4);

    int etiles = (E_TOT + TE - 1) / TE;          // 1352
    dist_kernel<<<etiles, 256, 0, stream>>>(ent, rot_v4, (float*)d_out);
}

// Round 10
// 177.977 us; speedup vs baseline: 1.0915x; 1.0915x over previous
//
#include <hip/hip_runtime.h>
#include <math.h>

#define DIMH 256        // D
#define NB   32         // batch
#define E_TOT 43234
#define TE   16         // entities per block  (2703 blocks = 10.6/CU, oversubscribed)
#define DK   32         // d-chunk staged in LDS
#define NC   (DIMH / DK)  // 8 chunks
// reference: phase = rel / (REL_RANGE/PI); REL_RANGE/PI = 0.03125/PI
#define PHASE_DIV 0.009947183943243459f

typedef float v4f __attribute__((ext_vector_type(4)));

// Kernel 1: rotate head by relation phase; planar layout:
// rot[b*256+d] = re_rot, rot[8192 + b*256+d] = im_rot.
__global__ __launch_bounds__(256) void rot_kernel(const float* __restrict__ head,
                                                  const float* __restrict__ rel,
                                                  float* __restrict__ rot) {
    int i = blockIdx.x * 256 + threadIdx.x;   // 0..8191
    int b = i >> 8;
    int d = i & 255;
    float re_h = head[b * 2 * DIMH + d];
    float im_h = head[b * 2 * DIMH + DIMH + d];
    float s, c;
    sincosf(rel[b * DIMH + d] / PHASE_DIV, &s, &c);
    rot[b * DIMH + d]             = re_h * c - im_h * s;
    rot[NB * DIMH + b * DIMH + d] = re_h * s + im_h * c;
}

__device__ __forceinline__ v4f sqrt4(v4f s) {
    v4f r;
    r.x = __builtin_amdgcn_sqrtf(s.x);
    r.y = __builtin_amdgcn_sqrtf(s.y);
    r.z = __builtin_amdgcn_sqrtf(s.z);
    r.w = __builtin_amdgcn_sqrtf(s.w);
    return r;   // trans pipe — overlaps main VALU (R9 showed NR-on-VALU is slower)
}

// Kernel 2: block = 16-entity tile x all 256 d, all 32 batches.
// KEY CHANGE vs R8: grid 1352 -> 2703 blocks. R8's grid fit entirely resident
// (no backfill queue) so the machine drained as blocks finished unevenly —
// occupancy pinned at ~half the co-resident bound every round. Now 10.6
// blocks/CU against a 6-block residency cap keeps a ~4.5-block queue per CU.
// Planar LDS quads: row = 8 v4f + 1 pad (36-float stride): ent reads 2-way
// b128 aliasing (free), rot reads 4-address broadcasts. 13.5 KB LDS.
// Per-thread tile: 2 batch x 1 entity; 2.5 pk + 1 sqrt per contrib (same as R8).
__global__ __launch_bounds__(256, 6) void dist_kernel(const float* __restrict__ ent,
                                                      const float* __restrict__ rot,
                                                      float* __restrict__ out) {
    __shared__ v4f s_er[TE][DK / 4 + 1];   // 16 x 9 x 16 B = 2.3 KB
    __shared__ v4f s_ei[TE][DK / 4 + 1];
    __shared__ v4f s_rr[NB][DK / 4 + 1];   // 32 x 9 x 16 B = 4.6 KB
    __shared__ v4f s_ri[NB][DK / 4 + 1];

    const int tid = threadIdx.x;
    const int eb  = blockIdx.x * TE;
    const int ep  = tid & 15;          // entity within tile
    const int bp  = tid >> 4;          // batch pair {2bp, 2bp+1}

    // ent staging: 256 tasks = 16 rows x 8 quads x {re,im}
    const int sh   = tid >> 7;                 // 0 = re plane, 1 = im plane
    const int srow = (tid >> 3) & 15;          // ent row in tile
    const int sq   = tid & 7;                  // quad: d = dk + 4*sq
    const int er   = min(eb + srow, E_TOT - 1);
    // rot staging: each thread loads re AND im for one (row, quad)
    const int rrow = tid >> 3;                 // 0..31
    const int rq   = tid & 7;

    float4 p_e, p_rr, p_ri;

    auto load_chunk = [&](int c) {
        const int dk = c * DK;
        p_e  = *reinterpret_cast<const float4*>(&ent[(size_t)er * (2 * DIMH) + sh * DIMH + dk + 4 * sq]);
        p_rr = *reinterpret_cast<const float4*>(&rot[rrow * DIMH + dk + 4 * rq]);
        p_ri = *reinterpret_cast<const float4*>(&rot[NB * DIMH + rrow * DIMH + dk + 4 * rq]);
    };

    v4f acc0, acc1;
    acc0 = 0.f; acc1 = 0.f;

    load_chunk(0);

    for (int c = 0; c < NC; ++c) {
        // ---- store prefetched regs to LDS
        {
            v4f e; e.x = p_e.x; e.y = p_e.y; e.z = p_e.z; e.w = p_e.w;
            (sh ? s_ei : s_er)[srow][sq] = e;
            v4f r0; r0.x = p_rr.x; r0.y = p_rr.y; r0.z = p_rr.z; r0.w = p_rr.w;
            v4f r1; r1.x = p_ri.x; r1.y = p_ri.y; r1.z = p_ri.z; r1.w = p_ri.w;
            s_rr[rrow][rq] = r0;
            s_ri[rrow][rq] = r1;
        }
        __syncthreads();

        // ---- issue next chunk's global loads (consumed after next barrier)
        if (c + 1 < NC) load_chunk(c + 1);

        #pragma unroll 4
        for (int q = 0; q < DK / 4; ++q) {
            v4f rr0 = s_rr[2 * bp][q];
            v4f rr1 = s_rr[2 * bp + 1][q];
            v4f ri0 = s_ri[2 * bp][q];
            v4f ri1 = s_ri[2 * bp + 1][q];
            v4f ere = s_er[ep][q];
            v4f eim = s_ei[ep][q];

            {   v4f a = rr0 - ere, b = ri0 - eim;
                acc0 += sqrt4(a * a + b * b); }
            {   v4f a = rr1 - ere, b = ri1 - eim;
                acc1 += sqrt4(a * a + b * b); }
        }
        __syncthreads();
    }

    const int e = eb + ep;
    if (e < E_TOT) {
        out[(size_t)(2 * bp) * E_TOT + e]     = 6.0f - (acc0.x + acc0.y + acc0.z + acc0.w);
        out[(size_t)(2 * bp + 1) * E_TOT + e] = 6.0f - (acc1.x + acc1.y + acc1.z + acc1.w);
    }
}

extern "C" void kernel_launch(void* const* d_in, const int* in_sizes, int n_in,
                              void* d_out, int out_size, void* d_ws, size_t ws_size,
                              hipStream_t stream) {
    const float* head = (const float*)d_in[0];   // (32, 512)
    const float* rel  = (const float*)d_in[1];   // (32, 256)
    const float* ent  = (const float*)d_in[2];   // (43234, 512)
    float* rot = (float*)d_ws;                   // 2 * 32 * 256 floats = 64 KB

    rot_kernel<<<(NB * DIMH) / 256, 256, 0, stream>>>(head, rel, rot);

    int etiles = (E_TOT + TE - 1) / TE;          // 2703
    dist_kernel<<<etiles, 256, 0, stream>>>(ent, rot, (float*)d_out);
}

// Round 11
// 176.285 us; speedup vs baseline: 1.1020x; 1.0096x over previous
//
#include <hip/hip_runtime.h>
#include <math.h>

#define DIMH 256        // D
#define NB   32         // batch
#define E_TOT 43234
#define TE_B 16         // entities per block (2703 blocks = 10.6/CU vs 4-block residency cap)
#define TE_C 2          // entities staged per chunk (4 KB LDS)
// reference: phase = rel / (REL_RANGE/PI); REL_RANGE/PI = 0.03125/PI
#define PHASE_DIV 0.009947183943243459f

typedef float v2f __attribute__((ext_vector_type(2)));

// Kernel 1: rotate head by relation phase; interleaved layout per (b, dpair):
// rot_v4[b*128+dp] = (re_2dp, re_2dp+1, im_2dp, im_2dp+1).
__global__ __launch_bounds__(256) void rot_kernel(const float* __restrict__ head,
                                                  const float* __restrict__ rel,
                                                  float4* __restrict__ rot_v4) {
    int i  = blockIdx.x * 256 + threadIdx.x;   // 0..4095
    int b  = i >> 7;
    int dp = i & 127;
    int d0 = dp * 2;
    float4 w;
    {
        float re_h = head[b * 2 * DIMH + d0];
        float im_h = head[b * 2 * DIMH + DIMH + d0];
        float s, c;
        sincosf(rel[b * DIMH + d0] / PHASE_DIV, &s, &c);
        w.x = re_h * c - im_h * s;
        w.z = re_h * s + im_h * c;
    }
    {
        float re_h = head[b * 2 * DIMH + d0 + 1];
        float im_h = head[b * 2 * DIMH + DIMH + d0 + 1];
        float s, c;
        sincosf(rel[b * DIMH + d0 + 1] / PHASE_DIV, &s, &c);
        w.y = re_h * c - im_h * s;
        w.w = re_h * s + im_h * c;
    }
    rot_v4[b * (DIMH / 2) + dp] = w;
}

__device__ __forceinline__ v2f sqrt2(v2f s) {
    v2f r;
    r.x = __builtin_amdgcn_sqrtf(s.x);   // trans pipe — overlaps main VALU (R9 lesson)
    r.y = __builtin_amdgcn_sqrtf(s.y);
    return r;
}

// Sum h over each 32-lane half of the wave, entirely on the VALU pipe (DPP).
// Result valid in lanes 31 and 63. row_shr prefix-sums within 16-rows, then
// row_bcast15 folds row0->row1 (and row2->row3).
__device__ __forceinline__ float dpp_reduce32(float h) {
    h += __int_as_float(__builtin_amdgcn_update_dpp(0, __float_as_int(h), 0x111, 0xf, 0xf, true)); // shr1
    h += __int_as_float(__builtin_amdgcn_update_dpp(0, __float_as_int(h), 0x112, 0xf, 0xf, true)); // shr2
    h += __int_as_float(__builtin_amdgcn_update_dpp(0, __float_as_int(h), 0x114, 0xf, 0xf, true)); // shr4
    h += __int_as_float(__builtin_amdgcn_update_dpp(0, __float_as_int(h), 0x118, 0xf, 0xf, true)); // shr8
    h += __int_as_float(__builtin_amdgcn_update_dpp(0, __float_as_int(h), 0x142, 0xf, 0xf, true)); // bcast15
    return h;
}

// Kernel 2 (RESTRUCTURED): thread = (batch-group bg 0..7) x (d-slice ds 0..31,
// 8 d each). rot lives in REGISTERS for the whole kernel (64 VGPRs) — LDS only
// streams entity data: per wave-entity 4 KB delivered for 2048 contribs
// = 2 B/contrib (R10 measured-floor currency was LDS delivered-bytes at 12 B).
// LDS layout s_e[e][unit u][ds]: u 0..3 = re d-pairs, 4..7 = im d-pairs;
// lane read addr stride 2 words -> 2-way b64 aliasing (measured-free family).
// Per-(b,e) sums complete after a 32-lane DPP reduction (VALU pipe, NOT
// ds_swizzle which would re-load the LDS pipe); lanes 31/63 store directly.
__global__ __launch_bounds__(256, 4) void dist_kernel(const float* __restrict__ ent,
                                                      const float4* __restrict__ rot_v4,
                                                      float* __restrict__ out) {
    __shared__ float2 s_e[TE_C][8][32];   // 4 KB

    const int tid = threadIdx.x;
    const int ds  = tid & 31;          // d-slice: d in [8*ds, 8*ds+8)
    const int bg  = tid >> 5;          // batch group: b = 4*bg + jj
    const int eb  = blockIdx.x * TE_B;

    // ---- rot -> registers (L2/L3-hot; 16 x b128 per thread, once per block)
    v2f rr[4][4], ri[4][4];
    #pragma unroll
    for (int jj = 0; jj < 4; ++jj) {
        const int b = bg * 4 + jj;
        #pragma unroll
        for (int p = 0; p < 4; ++p) {
            float4 w = rot_v4[b * (DIMH / 2) + ds * 4 + p];
            rr[jj][p].x = w.x; rr[jj][p].y = w.y;
            ri[jj][p].x = w.z; ri[jj][p].y = w.w;
        }
    }

    // ---- entity staging ids: 256 thr = 2 entities x 2 planes x 64 d-quads
    const int e_l   = tid >> 7;          // 0..1
    const int plane = (tid >> 6) & 1;    // 0 = re, 1 = im
    const int qd    = tid & 63;          // d = 4*qd .. 4*qd+3

    float4 pf;
    auto load_chunk = [&](int ch) {
        int eg = min(eb + ch * TE_C + e_l, E_TOT - 1);   // clamp tail; stores guarded
        pf = *reinterpret_cast<const float4*>(&ent[(size_t)eg * (2 * DIMH) + plane * DIMH + 4 * qd]);
    };

    load_chunk(0);

    for (int ch = 0; ch < TE_B / TE_C; ++ch) {
        // ---- stage prefetched quad as two d-pair float2s
        {
            const int dsw = qd >> 1;                       // (2qd)>>2
            const int u0  = ((qd & 1) ? 2 : 0) + plane * 4;
            float2 lo, hi;
            lo.x = pf.x; lo.y = pf.y;
            hi.x = pf.z; hi.y = pf.w;
            s_e[e_l][u0][dsw]     = lo;
            s_e[e_l][u0 + 1][dsw] = hi;
        }
        __syncthreads();

        if (ch + 1 < TE_B / TE_C) load_chunk(ch + 1);

        v2f acc[4][TE_C];
        #pragma unroll
        for (int jj = 0; jj < 4; ++jj)
            #pragma unroll
            for (int ee = 0; ee < TE_C; ++ee) { acc[jj][ee].x = 0.f; acc[jj][ee].y = 0.f; }

        #pragma unroll
        for (int ee = 0; ee < TE_C; ++ee) {
            v2f er[4], ei[4];
            #pragma unroll
            for (int p = 0; p < 4; ++p) {
                float2 a = s_e[ee][p][ds];
                float2 b = s_e[ee][p + 4][ds];
                er[p].x = a.x; er[p].y = a.y;
                ei[p].x = b.x; ei[p].y = b.y;
            }
            #pragma unroll
            for (int jj = 0; jj < 4; ++jj)
                #pragma unroll
                for (int p = 0; p < 4; ++p) {
                    v2f a = rr[jj][p] - er[p];
                    v2f b = ri[jj][p] - ei[p];
                    acc[jj][ee] += sqrt2(a * a + b * b);
                }
        }
        __syncthreads();   // LDS consumed; next chunk may stage

        // ---- DPP reduce over the 32 d-slices; lanes 31/63 hold full sums
        #pragma unroll
        for (int jj = 0; jj < 4; ++jj)
            #pragma unroll
            for (int ee = 0; ee < TE_C; ++ee) {
                float h = dpp_reduce32(acc[jj][ee].x + acc[jj][ee].y);
                const int e = eb + ch * TE_C + ee;
                if ((tid & 31) == 31 && e < E_TOT)
                    out[(size_t)(bg * 4 + jj) * E_TOT + e] = 6.0f - h;
            }
    }
}

extern "C" void kernel_launch(void* const* d_in, const int* in_sizes, int n_in,
                              void* d_out, int out_size, void* d_ws, size_t ws_size,
                              hipStream_t stream) {
    const float* head = (const float*)d_in[0];   // (32, 512)
    const float* rel  = (const float*)d_in[1];   // (32, 256)
    const float* ent  = (const float*)d_in[2];   // (43234, 512)
    float4* rot_v4 = (float4*)d_ws;              // 32 * 128 * 16 B = 64 KB

    rot_kernel<<<(NB * DIMH / 2) / 256, 256, 0, stream>>>(head, rel, rot_v4);

    int eblocks = (E_TOT + TE_B - 1) / TE_B;     // 2703
    dist_kernel<<<eblocks, 256, 0, stream>>>(ent, rot_v4, (float*)d_out);
}